// Round 19
// baseline (661.386 us; speedup 1.0000x reference)
//
#include <hip/hip_runtime.h>
#include <hip/hip_bf16.h>

#define N_NODES 100000
#define N_EDGES 1000000
#define EMB 64
#define NLAYER 4
#define NTILE 1563            // ceil(100000/64); last tile has 32 rows
#define NSHARD 16             // atomic-stat shards (kills deep same-address chains)
#define NBIN 196              // dst>>9 bins (512 nodes/bin) for XCD-local CSR build
#define NS1B 489              // ceil(1e6/2048) edge-pass blocks

typedef __hip_bfloat16 bf16;
typedef __attribute__((ext_vector_type(8))) short short8;
typedef __attribute__((ext_vector_type(4))) float f32x4;

static __device__ __forceinline__ float b2f(bf16 v) { return __bfloat162float(v); }
static __device__ __forceinline__ bf16 f2b(float v) { return __float2bfloat16(v); }
static __device__ __forceinline__ float lo16f(unsigned int v) {
    unsigned int t = v << 16; float f; __builtin_memcpy(&f, &t, 4); return f;
}
static __device__ __forceinline__ float hi16f(unsigned int v) {
    unsigned int t = v & 0xffff0000u; float f; __builtin_memcpy(&f, &t, 4); return f;
}

// -------- atom encoder: P[n,e] = sum_c atom_emb[c, x[n,c], e]; pre-affine buf Y ------
__global__ void k_atom(const int* __restrict__ x, const bf16* __restrict__ aemb,
                       bf16* __restrict__ P) {
    int tid = blockIdx.x * 256 + threadIdx.x;            // N*64 exactly
    int n = tid >> 6, e = tid & 63;
    float s = 0.f;
#pragma unroll
    for (int c = 0; c < 9; ++c) {
        int v = x[n * 9 + c];
        s += b2f(aemb[(c * 64 + v) * 64 + e]);
    }
    P[tid] = f2b(s);
}

// -------- combined bond table: cb[l][combo][c] = sum of 3 embeddings, combo 9-bit ----
__global__ void k_bond(const bf16* __restrict__ bemb, bf16* __restrict__ cb) {
    int idx = blockIdx.x * 256 + threadIdx.x;            // 4*512*64 = 131072
    int l = idx >> 15, r = idx & 32767;
    int combo = r >> 6, c = r & 63;
    int e0 = combo & 7, e1 = (combo >> 3) & 7, e2 = combo >> 6;
    float v = b2f(bemb[((l * 3 + 0) * 8 + e0) * 64 + c]) +
              b2f(bemb[((l * 3 + 1) * 8 + e1) * 64 + c]) +
              b2f(bemb[((l * 3 + 2) * 8 + e2) * 64 + c]);
    cb[idx] = f2b(v);
}

// ==== CSR build with ZERO scattered global atomics (R18-verified: ~50us chain) =======

// binc: per-block bin counts (LDS) -> bpart[blk][bin], plain stores
__global__ __launch_bounds__(256) void k_binc(const int* __restrict__ ei,
                                              int* __restrict__ bpart) {
    __shared__ int lc[NBIN];
    for (int i = threadIdx.x; i < NBIN; i += 256) lc[i] = 0;
    __syncthreads();
    int base = blockIdx.x * 2048;
#pragma unroll
    for (int k = 0; k < 8; ++k) {
        int e = base + k * 256 + threadIdx.x;
        if (e < N_EDGES) atomicAdd(&lc[ei[N_EDGES + e] >> 9], 1);
    }
    __syncthreads();
    for (int i = threadIdx.x; i < NBIN; i += 256) bpart[blockIdx.x * NBIN + i] = lc[i];
}

// binps: one block per bin -- exclusive scan over the 489 block partials (in-place)
__global__ __launch_bounds__(512) void k_binps(int* __restrict__ bpart,
                                               int* __restrict__ bcnt) {
    __shared__ int s[512];
    int bin = blockIdx.x, t = threadIdx.x;
    int v0 = (t < NS1B) ? bpart[t * NBIN + bin] : 0;
    s[t] = v0;
    __syncthreads();
    for (int d = 1; d < 512; d <<= 1) {                  // Hillis-Steele inclusive
        int v = (t >= d) ? s[t - d] : 0;
        __syncthreads();
        s[t] += v;
        __syncthreads();
    }
    if (t < NS1B) bpart[t * NBIN + bin] = s[t] - v0;     // exclusive within bin
    if (t == 511) bcnt[bin] = s[511];
}

// binbase: scan bcnt -> bbase; offs[N] = E (constant)
__global__ void k_binbase(const int* __restrict__ bcnt, int* __restrict__ bbase,
                          int* __restrict__ offs) {
    __shared__ int s[256];
    int t = threadIdx.x;
    int v0 = (t < NBIN) ? bcnt[t] : 0;
    s[t] = v0;
    __syncthreads();
    for (int d = 1; d < 256; d <<= 1) {
        int v = (t >= d) ? s[t - d] : 0;
        __syncthreads();
        s[t] += v;
        __syncthreads();
    }
    if (t < NBIN) bbase[t] = s[t] - v0;
    if (t == 0) offs[N_NODES] = N_EDGES;
}

// scat1: deterministic reservation gb = bbase + bpart_excl; rank via LDS atomic only
__global__ __launch_bounds__(256) void k_scat1(const int* __restrict__ ei,
                                               const int* __restrict__ ea,
                                               const int* __restrict__ bpart,
                                               const int* __restrict__ bbase,
                                               int2* __restrict__ tmp8,
                                               int* __restrict__ tmpd) {
    __shared__ int gb[NBIN], lcur[NBIN];
    for (int i = threadIdx.x; i < NBIN; i += 256) {
        gb[i] = bbase[i] + bpart[blockIdx.x * NBIN + i];
        lcur[i] = 0;
    }
    __syncthreads();
    int base = blockIdx.x * 2048;
#pragma unroll
    for (int k = 0; k < 8; ++k) {
        int e = base + k * 256 + threadIdx.x;
        if (e < N_EDGES) {
            int d = ei[N_EDGES + e];
            int bin = d >> 9;
            int pk = ea[e * 3] + (ea[e * 3 + 1] << 3) + (ea[e * 3 + 2] << 6);
            int r = atomicAdd(&lcur[bin], 1);
            int pos = gb[bin] + r;
            tmp8[pos] = make_int2(ei[e], pk);
            tmpd[pos] = d;
        }
    }
}

// scat2: one block per bin -- deg + offs-scan + cursor all in LDS; writes confined
// to this bin's csr window (one XCD owns every line it writes)
__global__ __launch_bounds__(512) void k_scat2(const int2* __restrict__ tmp8,
                                               const int* __restrict__ tmpd,
                                               const int* __restrict__ bbase,
                                               const int* __restrict__ bcnt,
                                               int* __restrict__ offs,
                                               int2* __restrict__ csr) {
    __shared__ int dg[512], sc[512], cur[512];
    int bin = blockIdx.x, t = threadIdx.x;
    dg[t] = 0;
    __syncthreads();
    int s0 = bbase[bin], cnt = bcnt[bin];
    for (int i = s0 + t; i < s0 + cnt; i += 512)         // local deg histogram
        atomicAdd(&dg[tmpd[i] & 511], 1);
    __syncthreads();
    int v0 = dg[t];
    sc[t] = v0;
    __syncthreads();
    for (int d = 1; d < 512; d <<= 1) {                  // block scan over 512 degs
        int v = (t >= d) ? sc[t - d] : 0;
        __syncthreads();
        sc[t] += v;
        __syncthreads();
    }
    int ex = s0 + sc[t] - v0;                            // global exclusive offset
    cur[t] = ex;
    int node = (bin << 9) + t;
    if (node < N_NODES) offs[node] = ex;
    __syncthreads();
    for (int i = s0 + t; i < s0 + cnt; i += 512) {       // scatter into bin window
        int d = tmpd[i];
        int pos = atomicAdd(&cur[d & 511], 1);
        csr[pos] = tmp8[i];
    }
}

// ---- aggregate, 2-edges-per-gather packing ------------------------------------------
// R18 counters: k_agg 54us, VALU 48%, HBM 18% -> gather-issue count is the gate.
// Each lane loads a uint (2 bf16 channels); 32 lanes cover a 128B row, so the wave's
// two 32-lane halves gather TWO edges' rows per instruction (lo half: even edges,
// hi half: odd edges). acc merged once at the end via shfl_xor(32). Addressing stays
// SGPR-base + 32-bit VGPR offset (readfirstlane'd indices; R10 lesson).
__global__ void k_agg(const bf16* __restrict__ P, const int* __restrict__ offs,
                      const int2* __restrict__ csr,
                      const bf16* __restrict__ cb, const bf16* __restrict__ eps,
                      const float* __restrict__ p2s, const bf16* __restrict__ g2,
                      const bf16* __restrict__ bb2, int layer,
                      bf16* __restrict__ G, float* __restrict__ p1s) {
    if (blockIdx.x < NSHARD) p1s[blockIdx.x * 256 + threadIdx.x] = 0.f;
    int tid = blockIdx.x * 256 + threadIdx.x;
    int lane = threadIdx.x & 63;
    int n = __builtin_amdgcn_readfirstlane(tid >> 6);    // uniform per wave
    int half = lane >> 5;                                // 0: even edges, 1: odd edges
    int l31 = lane & 31;
    int c0 = l31 * 2;                                    // this lane's channel pair
    int voff = l31 * 4;                                  // byte offset within 128B row
    float av0 = 1.f, cv0 = 0.f, av1 = 1.f, cv1 = 0.f, lo = -3.4e38f;
    if (layer > 0) {
        const float* pp = p2s + (layer - 1) * NSHARD * 128;
        float S0 = 0.f, Q0 = 0.f, S1 = 0.f, Q1 = 0.f;
#pragma unroll
        for (int s = 0; s < NSHARD; ++s) {
            S0 += pp[s * 128 + c0];     Q0 += pp[s * 128 + 64 + c0];
            S1 += pp[s * 128 + c0 + 1]; Q1 += pp[s * 128 + 64 + c0 + 1];
        }
        float m0 = S0 / (float)N_NODES;
        float va0 = fmaxf(Q0 / (float)N_NODES - m0 * m0, 0.f);
        av0 = b2f(g2[(layer - 1) * 64 + c0]) * rsqrtf(va0 + 1e-5f);
        cv0 = b2f(bb2[(layer - 1) * 64 + c0]) - m0 * av0;
        float m1 = S1 / (float)N_NODES;
        float va1 = fmaxf(Q1 / (float)N_NODES - m1 * m1, 0.f);
        av1 = b2f(g2[(layer - 1) * 64 + c0 + 1]) * rsqrtf(va1 + 1e-5f);
        cv1 = b2f(bb2[(layer - 1) * 64 + c0 + 1]) - m1 * av1;
        lo = 0.f;                                        // relu iff affine folded
    }
    const char* Pb = (const char*)P;
    const char* cblb = (const char*)(cb + layer * 512 * 64);
    float acc0 = 0.f, acc1 = 0.f;
    if (half == 0) {                                     // self term, lo half only
        unsigned int hv = *(const unsigned int*)(Pb + n * 128 + voff);
        float epsv = 1.f + b2f(eps[layer]);
        acc0 = epsv * fmaxf(av0 * lo16f(hv) + cv0, lo);
        acc1 = epsv * fmaxf(av1 * hi16f(hv) + cv1, lo);
    }
    int s0 = __builtin_amdgcn_readfirstlane(offs[n]);
    int s1 = __builtin_amdgcn_readfirstlane(offs[n + 1]);
    int i = s0;
    for (; i + 8 <= s1; i += 8) {                        // 4 pairs in flight
        int srA[4], epA[4], srB[4], epB[4];
#pragma unroll
        for (int u = 0; u < 4; ++u) {
            int2 e0 = csr[i + 2 * u];
            int2 e1 = csr[i + 2 * u + 1];
            srA[u] = __builtin_amdgcn_readfirstlane(e0.x);
            epA[u] = __builtin_amdgcn_readfirstlane(e0.y);
            srB[u] = __builtin_amdgcn_readfirstlane(e1.x);
            epB[u] = __builtin_amdgcn_readfirstlane(e1.y);
        }
        unsigned int hv[4], bv[4];
#pragma unroll
        for (int u = 0; u < 4; ++u) {
            int sre = half ? srB[u] : srA[u];
            int epe = half ? epB[u] : epA[u];
            hv[u] = *(const unsigned int*)(Pb + sre * 128 + voff);
            bv[u] = *(const unsigned int*)(cblb + epe * 128 + voff);
        }
#pragma unroll
        for (int u = 0; u < 4; ++u) {
            acc0 += fmaxf(fmaxf(av0 * lo16f(hv[u]) + cv0, lo) + lo16f(bv[u]), 0.f);
            acc1 += fmaxf(fmaxf(av1 * hi16f(hv[u]) + cv1, lo) + hi16f(bv[u]), 0.f);
        }
    }
    for (; i + 2 <= s1; i += 2) {                        // single pair
        int2 e0 = csr[i];
        int2 e1 = csr[i + 1];
        int srA = __builtin_amdgcn_readfirstlane(e0.x);
        int epA = __builtin_amdgcn_readfirstlane(e0.y);
        int srB = __builtin_amdgcn_readfirstlane(e1.x);
        int epB = __builtin_amdgcn_readfirstlane(e1.y);
        int sre = half ? srB : srA;
        int epe = half ? epB : epA;
        unsigned int hv = *(const unsigned int*)(Pb + sre * 128 + voff);
        unsigned int bv = *(const unsigned int*)(cblb + epe * 128 + voff);
        acc0 += fmaxf(fmaxf(av0 * lo16f(hv) + cv0, lo) + lo16f(bv), 0.f);
        acc1 += fmaxf(fmaxf(av1 * hi16f(hv) + cv1, lo) + hi16f(bv), 0.f);
    }
    if (i < s1) {                                        // odd tail: lo half only
        int2 e0 = csr[i];
        int sre = __builtin_amdgcn_readfirstlane(e0.x);
        int epe = __builtin_amdgcn_readfirstlane(e0.y);
        if (half == 0) {
            unsigned int hv = *(const unsigned int*)(Pb + sre * 128 + voff);
            unsigned int bv = *(const unsigned int*)(cblb + epe * 128 + voff);
            acc0 += fmaxf(fmaxf(av0 * lo16f(hv) + cv0, lo) + lo16f(bv), 0.f);
            acc1 += fmaxf(fmaxf(av1 * hi16f(hv) + cv1, lo) + hi16f(bv), 0.f);
        }
    }
    acc0 += __shfl_xor(acc0, 32, 64);                    // merge even/odd partials
    acc1 += __shfl_xor(acc1, 32, 64);
    if (half == 0) {
        bf16 r0 = f2b(acc0), r1 = f2b(acc1);
        unsigned short u0, u1;
        __builtin_memcpy(&u0, &r0, 2);
        __builtin_memcpy(&u1, &r1, 2);
        unsigned int pk = ((unsigned int)u1 << 16) | u0;
        *(unsigned int*)((char*)G + n * 128 + voff) = pk;
    }
}

// ---- transpose W1 -> W1T [L][128][64], W2 -> W2T [L][64][128] (once per launch) -----
__global__ void k_wt(const bf16* __restrict__ W1, const bf16* __restrict__ W2,
                     bf16* __restrict__ W1T, bf16* __restrict__ W2T) {
    int idx = blockIdx.x * 256 + threadIdx.x;            // 4*8192 threads
    int l = idx >> 13, r = idx & 8191;
    int k = r >> 7, n = r & 127;                         // W1: [64][128]
    W1T[l * 8192 + n * 64 + k] = W1[idx];
    int k2 = r >> 6, n2 = r & 63;                        // W2: [128][64]
    W2T[l * 8192 + n2 * 128 + k2] = W2[idx];
}

// ---- MLP1 stats via MFMA: z@W1+b1, tree-reduced then SHARDED atomic into p1s --------
// Weights direct from global (L1-hot across blocks); LDS 13.3KB -> occupancy cap.
__global__ __launch_bounds__(256) void k_mlp1s(
    const bf16* __restrict__ X, const bf16* __restrict__ W1T, const bf16* __restrict__ b1,
    int layer, float* __restrict__ p1s, float* __restrict__ p2s) {
    __shared__ bf16 zt[64 * 72];                         // 9216 B
    __shared__ float ps[4][4][32];                       // 2048 B
    __shared__ float qs[4][4][32];                       // 2048 B -> 13312 B total
    if (blockIdx.x < NSHARD && threadIdx.x < 128)
        p2s[(layer * NSHARD + blockIdx.x) * 128 + threadIdx.x] = 0.f;
    const bf16* Wl = W1T + layer * 8192;
    int r0 = blockIdx.x * 64;
    int nrows = min(64, N_NODES - r0);
    for (int i = threadIdx.x; i < 512; i += 256) {       // 64 rows x 8 chunks of 8
        int r = i >> 3, c = (i & 7) * 8;
        short8 v = {};
        if (r < nrows) v = *(const short8*)&X[(r0 + r) * 64 + c];
        *(short8*)&zt[r * 72 + c] = v;
    }
    __syncthreads();
    int wid = threadIdx.x >> 6;                          // wave 0..3 -> N-slice of 32
    int l = threadIdx.x & 63;
    int l15 = l & 15, lq = l >> 4;
    f32x4 acc[4][2];
#pragma unroll
    for (int m = 0; m < 4; ++m)
#pragma unroll
        for (int n = 0; n < 2; ++n) acc[m][n] = (f32x4){0.f, 0.f, 0.f, 0.f};
#pragma unroll
    for (int s = 0; s < 2; ++s) {
        short8 a[4], b[2];
#pragma unroll
        for (int m = 0; m < 4; ++m)
            a[m] = *(const short8*)&zt[(m * 16 + l15) * 72 + s * 32 + lq * 8];
#pragma unroll
        for (int n = 0; n < 2; ++n)
            b[n] = *(const short8*)&Wl[(wid * 32 + n * 16 + l15) * 64 + s * 32 + lq * 8];
#pragma unroll
        for (int m = 0; m < 4; ++m)
#pragma unroll
            for (int n = 0; n < 2; ++n)
                acc[m][n] = __builtin_amdgcn_mfma_f32_16x16x32_bf16(a[m], b[n], acc[m][n], 0, 0, 0);
    }
    float bb[2], cs[2] = {0.f, 0.f}, cq[2] = {0.f, 0.f};
#pragma unroll
    for (int n = 0; n < 2; ++n) bb[n] = b2f(b1[layer * 128 + wid * 32 + n * 16 + l15]);
#pragma unroll
    for (int m = 0; m < 4; ++m)
#pragma unroll
        for (int r = 0; r < 4; ++r) {
            int row = m * 16 + lq * 4 + r;
            if (row < nrows) {
#pragma unroll
                for (int n = 0; n < 2; ++n) {
                    float v = acc[m][n][r] + bb[n];
                    cs[n] += v; cq[n] += v * v;
                }
            }
        }
#pragma unroll
    for (int n = 0; n < 2; ++n) {
        ps[wid][lq][n * 16 + l15] = cs[n];
        qs[wid][lq][n * 16 + l15] = cq[n];
    }
    __syncthreads();
    if (threadIdx.x < 128) {
        int t = threadIdx.x, ww = t >> 5, cc = t & 31;   // col = ww*32 + cc = t
        float S = 0.f, Q = 0.f;
#pragma unroll
        for (int s4 = 0; s4 < 4; ++s4) { S += ps[ww][s4][cc]; Q += qs[ww][s4][cc]; }
        int sh = blockIdx.x & (NSHARD - 1);
        atomicAdd(&p1s[sh * 256 + t], S);
        atomicAdd(&p1s[sh * 256 + 128 + t], Q);
    }
}

// ---- MLP2 fused via MFMA: BN1 folded per-thread from sharded p1s; stats to p2s ------
// Writes PRE-affine z2 to Y. Weights direct from global; LDS 28.7KB (5 blk/CU).
__global__ __launch_bounds__(256) void k_mlp2(
    const bf16* __restrict__ W1T, const bf16* __restrict__ b1,
    const bf16* __restrict__ g1, const bf16* __restrict__ bb1,
    const float* __restrict__ p1s,
    const bf16* __restrict__ W2T, const bf16* __restrict__ bias2, int layer,
    const bf16* __restrict__ X, bf16* __restrict__ Y, float* __restrict__ p2s) {
    __shared__ bf16 zt[64 * 72];                         // 9216 B; reused to stage z2 out
    __shared__ bf16 yt[64 * 136];                        // 17408 B
    __shared__ float ps2[4][4][16];                      // 1024 B
    __shared__ float qs2[4][4][16];                      // 1024 B  -> total 28672 B
    const bf16* W1l = W1T + layer * 8192;
    const bf16* W2l = W2T + layer * 8192;
    int r0 = blockIdx.x * 64;
    int nrows = min(64, N_NODES - r0);
    for (int i = threadIdx.x; i < 512; i += 256) {
        int r = i >> 3, c = (i & 7) * 8;
        short8 v = {};
        if (r < nrows) v = *(const short8*)&X[(r0 + r) * 64 + c];
        *(short8*)&zt[r * 72 + c] = v;
    }
    __syncthreads();
    int wid = threadIdx.x >> 6;
    int l = threadIdx.x & 63;
    int l15 = l & 15, lq = l >> 4;
    {   // stage 1: 64x128 = 4 waves x (4 M-frags x 2 N-frags), K=64
        f32x4 acc[4][2];
#pragma unroll
        for (int m = 0; m < 4; ++m)
#pragma unroll
            for (int n = 0; n < 2; ++n) acc[m][n] = (f32x4){0.f, 0.f, 0.f, 0.f};
#pragma unroll
        for (int s = 0; s < 2; ++s) {
            short8 a[4], b[2];
#pragma unroll
            for (int m = 0; m < 4; ++m)
                a[m] = *(const short8*)&zt[(m * 16 + l15) * 72 + s * 32 + lq * 8];
#pragma unroll
            for (int n = 0; n < 2; ++n)
                b[n] = *(const short8*)&W1l[(wid * 32 + n * 16 + l15) * 64 + s * 32 + lq * 8];
#pragma unroll
            for (int m = 0; m < 4; ++m)
#pragma unroll
                for (int n = 0; n < 2; ++n)
                    acc[m][n] = __builtin_amdgcn_mfma_f32_16x16x32_bf16(a[m], b[n], acc[m][n], 0, 0, 0);
        }
        float aav[2], ccv[2], bbv[2];
#pragma unroll
        for (int n = 0; n < 2; ++n) {
            int col = wid * 32 + n * 16 + l15;
            float S = 0.f, Q = 0.f;
#pragma unroll
            for (int s4 = 0; s4 < NSHARD; ++s4) {
                S += p1s[s4 * 256 + col];
                Q += p1s[s4 * 256 + 128 + col];
            }
            float mean = S / (float)N_NODES;
            float var = fmaxf(Q / (float)N_NODES - mean * mean, 0.f);
            aav[n] = b2f(g1[layer * 128 + col]) * rsqrtf(var + 1e-5f);
            ccv[n] = b2f(bb1[layer * 128 + col]) - mean * aav[n];
            bbv[n] = b2f(b1[layer * 128 + col]);
        }
#pragma unroll
        for (int m = 0; m < 4; ++m)
#pragma unroll
            for (int n = 0; n < 2; ++n)
#pragma unroll
                for (int r = 0; r < 4; ++r) {
                    int row = m * 16 + lq * 4 + r;
                    float v = fmaxf(aav[n] * (acc[m][n][r] + bbv[n]) + ccv[n], 0.f);
                    yt[row * 136 + wid * 32 + n * 16 + l15] = f2b(v);
                }
    }
    __syncthreads();                                     // yt complete (cross-wave dep)
    {   // stage 2: 64x64 = 4 waves x (4 M-frags x 1 N-frag), K=128
        f32x4 acc2[4];
#pragma unroll
        for (int m = 0; m < 4; ++m) acc2[m] = (f32x4){0.f, 0.f, 0.f, 0.f};
#pragma unroll
        for (int s = 0; s < 4; ++s) {
            short8 a[4];
            short8 b = *(const short8*)&W2l[(wid * 16 + l15) * 128 + s * 32 + lq * 8];
#pragma unroll
            for (int m = 0; m < 4; ++m)
                a[m] = *(const short8*)&yt[(m * 16 + l15) * 136 + s * 32 + lq * 8];
#pragma unroll
            for (int m = 0; m < 4; ++m)
                acc2[m] = __builtin_amdgcn_mfma_f32_16x16x32_bf16(a[m], b, acc2[m], 0, 0, 0);
        }
        float bb2 = b2f(bias2[layer * 64 + wid * 16 + l15]);
        float cs = 0.f, cq = 0.f;
#pragma unroll
        for (int m = 0; m < 4; ++m)
#pragma unroll
            for (int r = 0; r < 4; ++r) {
                int row = m * 16 + lq * 4 + r;
                float v = acc2[m][r] + bb2;
                zt[row * 72 + wid * 16 + l15] = f2b(v);  // zt dead since stage-1 sync
                if (row < nrows) { cs += v; cq += v * v; }
            }
        ps2[wid][lq][l15] = cs;
        qs2[wid][lq][l15] = cq;
    }
    __syncthreads();
    for (int i = threadIdx.x; i < 512; i += 256) {       // coalesced z2 store via zt
        int r = i >> 3, c = (i & 7) * 8;
        if (r < nrows)
            *(short8*)&Y[(r0 + r) * 64 + c] = *(const short8*)&zt[r * 72 + c];
    }
    if (threadIdx.x < 64) {
        int ww = threadIdx.x >> 4, cc = threadIdx.x & 15; // col = ww*16+cc = threadIdx.x
        float S = 0.f, Q = 0.f;
#pragma unroll
        for (int s4 = 0; s4 < 4; ++s4) { S += ps2[ww][s4][cc]; Q += qs2[ww][s4][cc]; }
        int sh = blockIdx.x & (NSHARD - 1);
        atomicAdd(&p2s[(layer * NSHARD + sh) * 128 + threadIdx.x], S);
        atomicAdd(&p2s[(layer * NSHARD + sh) * 128 + 64 + threadIdx.x], Q);
    }
}

// ---- final: apply layer-3 affine (no relu), bf16 round, sanitize --------------------
// Sanitizer: NaN AND Inf/huge -> 0 (R17-proven; R18's NaN-only check leaked Inf).
__global__ void k_out(const bf16* __restrict__ P, const float* __restrict__ p2s,
                      const bf16* __restrict__ g2, const bf16* __restrict__ bb2,
                      const int* __restrict__ batch, float* __restrict__ out) {
    int tid = blockIdx.x * 256 + threadIdx.x;
    int c = tid & 63;
    const float* pp = p2s + 3 * NSHARD * 128;
    float S = 0.f, Q = 0.f;
#pragma unroll
    for (int s = 0; s < NSHARD; ++s) { S += pp[s * 128 + c]; Q += pp[s * 128 + 64 + c]; }
    float mean = S / (float)N_NODES;
    float var = fmaxf(Q / (float)N_NODES - mean * mean, 0.f);
    float av = b2f(g2[3 * 64 + c]) * rsqrtf(var + 1e-5f);
    float cv = b2f(bb2[3 * 64 + c]) - mean * av;
    float v = b2f(f2b(av * b2f(P[tid]) + cv));           // keep prior bf16 rounding
    out[tid] = (v != v || fabsf(v) > 1e20f) ? 0.f : v;
    if (tid < N_NODES) out[N_NODES * EMB + tid] = (float)batch[tid];
}

extern "C" void kernel_launch(void* const* d_in, const int* in_sizes, int n_in,
                              void* d_out, int out_size, void* d_ws, size_t ws_size,
                              hipStream_t stream) {
    (void)in_sizes; (void)n_in; (void)out_size; (void)ws_size;
    const int* x     = (const int*)d_in[0];
    const int* ei    = (const int*)d_in[1];
    const int* ea    = (const int*)d_in[2];
    const int* batch = (const int*)d_in[3];
    const bf16* aemb = (const bf16*)d_in[4];
    const bf16* bemb = (const bf16*)d_in[5];
    const bf16* eps  = (const bf16*)d_in[6];
    const bf16* W1   = (const bf16*)d_in[7];
    const bf16* b1   = (const bf16*)d_in[8];
    const bf16* g1   = (const bf16*)d_in[9];
    const bf16* bb1  = (const bf16*)d_in[10];
    const bf16* W2   = (const bf16*)d_in[11];
    const bf16* b2   = (const bf16*)d_in[12];
    const bf16* g2   = (const bf16*)d_in[13];
    const bf16* bb2  = (const bf16*)d_in[14];

    // R14/R17-measured ABI: d_out is fp32 storage (26 MB), compared in bf16 space.
    bf16* Y = (bf16*)d_ws;                               // pre-affine activations
    char* ob = (char*)d_out;
    bf16* X       = (bf16*)ob;                           // agg output [0 : 12.8M)
    int2* tmp8    = (int2*)ob;                           // scat1 payload [0 : 8M) (X dead)
    int*  tmpd    = (int*)(ob + 8000000);                // scat1 dst [8M : 12M)
    int*  offs    = (int*)(ob + 13200000);               // 100001 ints -> 13,600,004
    int2* csr     = (int2*)(ob + 14000008);              // 8 MB (src,combo) -> 22,000,008
    float* p1s    = (float*)(ob + 22000008);             // 16 shards x 256 f -> 22,016,392
    float* p2s    = (float*)(ob + 22016392);             // 4 x 16 x 128 f -> 22,049,160
    int*  bpart   = (int*)(ob + 22049160);               // 489*196 ints -> 22,432,536
    int*  bcnt    = (int*)(ob + 22432536);               // NBIN ints -> 22,433,320
    int*  bbase   = (int*)(ob + 22433320);               // NBIN ints -> 22,434,104
    bf16* w1t     = (bf16*)(ob + 22434112);              // 64 KB [L][128][64] (16B-align)
    bf16* w2t     = (bf16*)(ob + 22499648);              // 64 KB [L][64][128]
    bf16* cbt     = (bf16*)(ob + 22565184);              // 256 KB [L][512][64] -> 22,827,328

    k_atom<<<25000, 256, 0, stream>>>(x, aemb, Y);
    k_wt<<<128, 256, 0, stream>>>(W1, W2, w1t, w2t);
    k_bond<<<512, 256, 0, stream>>>(bemb, cbt);
    k_binc<<<NS1B, 256, 0, stream>>>(ei, bpart);
    k_binps<<<NBIN, 512, 0, stream>>>(bpart, bcnt);
    k_binbase<<<1, 256, 0, stream>>>(bcnt, bbase, offs);
    k_scat1<<<NS1B, 256, 0, stream>>>(ei, ea, bpart, bbase, tmp8, tmpd);
    k_scat2<<<NBIN, 512, 0, stream>>>(tmp8, tmpd, bbase, bcnt, offs, csr);

    for (int l = 0; l < NLAYER; ++l) {
        k_agg<<<25000, 256, 0, stream>>>(Y, offs, csr, cbt, eps,
                                         p2s, g2, bb2, l, X, p1s);
        k_mlp1s<<<NTILE, 256, 0, stream>>>(X, w1t, b1, l, p1s, p2s);
        k_mlp2<<<NTILE, 256, 0, stream>>>(w1t, b1, g1, bb1, p1s, w2t, b2, l, X, Y, p2s);
    }
    k_out<<<25000, 256, 0, stream>>>(Y, p2s, g2, bb2, batch, (float*)d_out);
}

// Round 22
// 491.161 us; speedup vs baseline: 1.3466x; 1.3466x over previous
//
#include <hip/hip_runtime.h>
#include <hip/hip_bf16.h>

#define N_NODES 100000
#define N_EDGES 1000000
#define EMB 64
#define NLAYER 4
#define NTILE 1563            // ceil(100000/64); last tile has 32 rows
#define NSHARD 16             // atomic-stat shards (kills deep same-address chains)
#define NBIN 196              // dst>>9 bins (512 nodes/bin) for XCD-local CSR build
#define NS1B 489              // ceil(1e6/2048) edge-pass blocks

typedef __hip_bfloat16 bf16;
typedef __attribute__((ext_vector_type(8))) short short8;
typedef __attribute__((ext_vector_type(4))) float f32x4;

static __device__ __forceinline__ float b2f(bf16 v) { return __bfloat162float(v); }
static __device__ __forceinline__ bf16 f2b(float v) { return __float2bfloat16(v); }

// -------- atom encoder: P[n,e] = sum_c atom_emb[c, x[n,c], e]; pre-affine buf Y ------
// R19: n and x[n*9+c] are WAVE-UNIFORM (64 lanes per node) -> readfirstlane makes the
// 9 index loads scalar and the aemb gathers SGPR-base + lane offset (R10 pattern).
__global__ void k_atom(const int* __restrict__ x, const bf16* __restrict__ aemb,
                       bf16* __restrict__ P) {
    int tid = blockIdx.x * 256 + threadIdx.x;            // N*64 exactly
    int n = __builtin_amdgcn_readfirstlane(tid >> 6), e = tid & 63;
    float s = 0.f;
#pragma unroll
    for (int c = 0; c < 9; ++c) {
        int v = __builtin_amdgcn_readfirstlane(x[n * 9 + c]);
        s += b2f(aemb[(c * 64 + v) * 64 + e]);
    }
    P[(size_t)n * 64 + e] = f2b(s);
}

// -------- combined bond table: cb[l][combo][c] = sum of 3 embeddings, combo 9-bit ----
__global__ void k_bond(const bf16* __restrict__ bemb, bf16* __restrict__ cb) {
    int idx = blockIdx.x * 256 + threadIdx.x;            // 4*512*64 = 131072
    int l = idx >> 15, r = idx & 32767;
    int combo = r >> 6, c = r & 63;
    int e0 = combo & 7, e1 = (combo >> 3) & 7, e2 = combo >> 6;
    float v = b2f(bemb[((l * 3 + 0) * 8 + e0) * 64 + c]) +
              b2f(bemb[((l * 3 + 1) * 8 + e1) * 64 + c]) +
              b2f(bemb[((l * 3 + 2) * 8 + e2) * 64 + c]);
    cb[idx] = f2b(v);
}

// ==== CSR build with ZERO scattered global atomics (R18-verified: ~50us chain) =======

// binc: per-block bin counts (LDS) -> bpart[blk][bin], plain stores
__global__ __launch_bounds__(256) void k_binc(const int* __restrict__ ei,
                                              int* __restrict__ bpart) {
    __shared__ int lc[NBIN];
    for (int i = threadIdx.x; i < NBIN; i += 256) lc[i] = 0;
    __syncthreads();
    int base = blockIdx.x * 2048;
#pragma unroll
    for (int k = 0; k < 8; ++k) {
        int e = base + k * 256 + threadIdx.x;
        if (e < N_EDGES) atomicAdd(&lc[ei[N_EDGES + e] >> 9], 1);
    }
    __syncthreads();
    for (int i = threadIdx.x; i < NBIN; i += 256) bpart[blockIdx.x * NBIN + i] = lc[i];
}

// binps: one block per bin -- exclusive scan over the 489 block partials (in-place)
__global__ __launch_bounds__(512) void k_binps(int* __restrict__ bpart,
                                               int* __restrict__ bcnt) {
    __shared__ int s[512];
    int bin = blockIdx.x, t = threadIdx.x;
    int v0 = (t < NS1B) ? bpart[t * NBIN + bin] : 0;
    s[t] = v0;
    __syncthreads();
    for (int d = 1; d < 512; d <<= 1) {                  // Hillis-Steele inclusive
        int v = (t >= d) ? s[t - d] : 0;
        __syncthreads();
        s[t] += v;
        __syncthreads();
    }
    if (t < NS1B) bpart[t * NBIN + bin] = s[t] - v0;     // exclusive within bin
    if (t == 511) bcnt[bin] = s[511];
}

// binbase: scan bcnt -> bbase; offs[N] = E (constant)
__global__ void k_binbase(const int* __restrict__ bcnt, int* __restrict__ bbase,
                          int* __restrict__ offs) {
    __shared__ int s[256];
    int t = threadIdx.x;
    int v0 = (t < NBIN) ? bcnt[t] : 0;
    s[t] = v0;
    __syncthreads();
    for (int d = 1; d < 256; d <<= 1) {
        int v = (t >= d) ? s[t - d] : 0;
        __syncthreads();
        s[t] += v;
        __syncthreads();
    }
    if (t < NBIN) bbase[t] = s[t] - v0;
    if (t == 0) offs[N_NODES] = N_EDGES;
}

// scat1: deterministic reservation gb = bbase + bpart_excl; rank via LDS atomic only
__global__ __launch_bounds__(256) void k_scat1(const int* __restrict__ ei,
                                               const int* __restrict__ ea,
                                               const int* __restrict__ bpart,
                                               const int* __restrict__ bbase,
                                               int2* __restrict__ tmp8,
                                               int* __restrict__ tmpd) {
    __shared__ int gb[NBIN], lcur[NBIN];
    for (int i = threadIdx.x; i < NBIN; i += 256) {
        gb[i] = bbase[i] + bpart[blockIdx.x * NBIN + i];
        lcur[i] = 0;
    }
    __syncthreads();
    int base = blockIdx.x * 2048;
#pragma unroll
    for (int k = 0; k < 8; ++k) {
        int e = base + k * 256 + threadIdx.x;
        if (e < N_EDGES) {
            int d = ei[N_EDGES + e];
            int bin = d >> 9;
            int pk = ea[e * 3] + (ea[e * 3 + 1] << 3) + (ea[e * 3 + 2] << 6);
            int r = atomicAdd(&lcur[bin], 1);
            int pos = gb[bin] + r;
            tmp8[pos] = make_int2(ei[e], pk);
            tmpd[pos] = d;
        }
    }
}

// scat2: one block per bin -- deg + offs-scan + cursor all in LDS; writes confined
// to this bin's csr window (one XCD owns every line it writes)
__global__ __launch_bounds__(512) void k_scat2(const int2* __restrict__ tmp8,
                                               const int* __restrict__ tmpd,
                                               const int* __restrict__ bbase,
                                               const int* __restrict__ bcnt,
                                               int* __restrict__ offs,
                                               int2* __restrict__ csr) {
    __shared__ int dg[512], sc[512], cur[512];
    int bin = blockIdx.x, t = threadIdx.x;
    dg[t] = 0;
    __syncthreads();
    int s0 = bbase[bin], cnt = bcnt[bin];
    for (int i = s0 + t; i < s0 + cnt; i += 512)         // local deg histogram
        atomicAdd(&dg[tmpd[i] & 511], 1);
    __syncthreads();
    int v0 = dg[t];
    sc[t] = v0;
    __syncthreads();
    for (int d = 1; d < 512; d <<= 1) {                  // block scan over 512 degs
        int v = (t >= d) ? sc[t - d] : 0;
        __syncthreads();
        sc[t] += v;
        __syncthreads();
    }
    int ex = s0 + sc[t] - v0;                            // global exclusive offset
    cur[t] = ex;
    int node = (bin << 9) + t;
    if (node < N_NODES) offs[node] = ex;
    __syncthreads();
    for (int i = s0 + t; i < s0 + cnt; i += 512) {       // scatter into bin window
        int d = tmpd[i];
        int pos = atomicAdd(&cur[d & 511], 1);
        csr[pos] = tmp8[i];
    }
}

// ---- aggregate with folded BN-affine (summed from 16-sharded atomic stats) ----------
// R18-MEASURED version (54us): one channel per lane, SGPR-base gathers via
// readfirstlane'd wave-uniform indices. R19 lesson: 2-edge packing with a per-lane
// half-select makes addresses divergent and DOUBLES the time -- do not repeat.
__global__ void k_agg(const bf16* __restrict__ P, const int* __restrict__ offs,
                      const int2* __restrict__ csr,
                      const bf16* __restrict__ cb, const bf16* __restrict__ eps,
                      const float* __restrict__ p2s, const bf16* __restrict__ g2,
                      const bf16* __restrict__ bb2, int layer,
                      bf16* __restrict__ G, float* __restrict__ p1s) {
    if (blockIdx.x < NSHARD) p1s[blockIdx.x * 256 + threadIdx.x] = 0.f;
    int tid = blockIdx.x * 256 + threadIdx.x;
    int c = tid & 63;
    int n = __builtin_amdgcn_readfirstlane(tid >> 6);    // uniform per wave
    float av = 1.f, cv = 0.f, lo = -3.4e38f;
    if (layer > 0) {
        const float* pp = p2s + (layer - 1) * NSHARD * 128;
        float S = 0.f, Q = 0.f;
#pragma unroll
        for (int s = 0; s < NSHARD; ++s) { S += pp[s * 128 + c]; Q += pp[s * 128 + 64 + c]; }
        float mean = S / (float)N_NODES;
        float var = fmaxf(Q / (float)N_NODES - mean * mean, 0.f);
        av = b2f(g2[(layer - 1) * 64 + c]) * rsqrtf(var + 1e-5f);
        cv = b2f(bb2[(layer - 1) * 64 + c]) - mean * av;
        lo = 0.f;                                        // relu iff affine folded
    }
    const bf16* cbl = cb + layer * 512 * 64;
    float hself = fmaxf(av * b2f(P[(size_t)n * 64 + c]) + cv, lo);
    float acc = (1.f + b2f(eps[layer])) * hself;
    int s0 = __builtin_amdgcn_readfirstlane(offs[n]);
    int s1 = __builtin_amdgcn_readfirstlane(offs[n + 1]);
    int i = s0;
    for (; i + 8 <= s1; i += 8) {                        // 8 independent gather chains
        int sr[8], ep[8];
        float hv[8], bv[8];
#pragma unroll
        for (int u = 0; u < 8; ++u) {
            int2 ed = csr[i + u];
            sr[u] = __builtin_amdgcn_readfirstlane(ed.x);
            ep[u] = __builtin_amdgcn_readfirstlane(ed.y);
        }
#pragma unroll
        for (int u = 0; u < 8; ++u) hv[u] = b2f(P[(size_t)sr[u] * 64 + c]);
#pragma unroll
        for (int u = 0; u < 8; ++u) bv[u] = b2f(cbl[(size_t)ep[u] * 64 + c]);
#pragma unroll
        for (int u = 0; u < 8; ++u)
            acc += fmaxf(fmaxf(av * hv[u] + cv, lo) + bv[u], 0.f);
    }
    for (; i + 4 <= s1; i += 4) {
        int sr[4], ep[4];
        float hv[4], bv[4];
#pragma unroll
        for (int u = 0; u < 4; ++u) {
            int2 ed = csr[i + u];
            sr[u] = __builtin_amdgcn_readfirstlane(ed.x);
            ep[u] = __builtin_amdgcn_readfirstlane(ed.y);
        }
#pragma unroll
        for (int u = 0; u < 4; ++u) hv[u] = b2f(P[(size_t)sr[u] * 64 + c]);
#pragma unroll
        for (int u = 0; u < 4; ++u) bv[u] = b2f(cbl[(size_t)ep[u] * 64 + c]);
#pragma unroll
        for (int u = 0; u < 4; ++u)
            acc += fmaxf(fmaxf(av * hv[u] + cv, lo) + bv[u], 0.f);
    }
    for (; i < s1; ++i) {
        int2 ed = csr[i];
        int sr = __builtin_amdgcn_readfirstlane(ed.x);
        int ep = __builtin_amdgcn_readfirstlane(ed.y);
        float m = fmaxf(av * b2f(P[(size_t)sr * 64 + c]) + cv, lo) +
                  b2f(cbl[(size_t)ep * 64 + c]);
        acc += fmaxf(m, 0.f);
    }
    G[tid] = f2b(acc);
}

// ---- transpose W1 -> W1T [L][128][64], W2 -> W2T [L][64][128] (once per launch) -----
__global__ void k_wt(const bf16* __restrict__ W1, const bf16* __restrict__ W2,
                     bf16* __restrict__ W1T, bf16* __restrict__ W2T) {
    int idx = blockIdx.x * 256 + threadIdx.x;            // 4*8192 threads
    int l = idx >> 13, r = idx & 8191;
    int k = r >> 7, n = r & 127;                         // W1: [64][128]
    W1T[l * 8192 + n * 64 + k] = W1[idx];
    int k2 = r >> 6, n2 = r & 63;                        // W2: [128][64]
    W2T[l * 8192 + n2 * 128 + k2] = W2[idx];
}

// ---- MLP1 stats via MFMA: z@W1+b1, tree-reduced then SHARDED atomic into p1s --------
// Weights direct from global (L1-hot across blocks); LDS 13.3KB -> occupancy cap.
__global__ __launch_bounds__(256) void k_mlp1s(
    const bf16* __restrict__ X, const bf16* __restrict__ W1T, const bf16* __restrict__ b1,
    int layer, float* __restrict__ p1s, float* __restrict__ p2s) {
    __shared__ bf16 zt[64 * 72];                         // 9216 B
    __shared__ float ps[4][4][32];                       // 2048 B
    __shared__ float qs[4][4][32];                       // 2048 B -> 13312 B total
    if (blockIdx.x < NSHARD && threadIdx.x < 128)
        p2s[(layer * NSHARD + blockIdx.x) * 128 + threadIdx.x] = 0.f;
    const bf16* Wl = W1T + layer * 8192;
    int r0 = blockIdx.x * 64;
    int nrows = min(64, N_NODES - r0);
    for (int i = threadIdx.x; i < 512; i += 256) {       // 64 rows x 8 chunks of 8
        int r = i >> 3, c = (i & 7) * 8;
        short8 v = {};
        if (r < nrows) v = *(const short8*)&X[(r0 + r) * 64 + c];
        *(short8*)&zt[r * 72 + c] = v;
    }
    __syncthreads();
    int wid = threadIdx.x >> 6;                          // wave 0..3 -> N-slice of 32
    int l = threadIdx.x & 63;
    int l15 = l & 15, lq = l >> 4;
    f32x4 acc[4][2];
#pragma unroll
    for (int m = 0; m < 4; ++m)
#pragma unroll
        for (int n = 0; n < 2; ++n) acc[m][n] = (f32x4){0.f, 0.f, 0.f, 0.f};
#pragma unroll
    for (int s = 0; s < 2; ++s) {
        short8 a[4], b[2];
#pragma unroll
        for (int m = 0; m < 4; ++m)
            a[m] = *(const short8*)&zt[(m * 16 + l15) * 72 + s * 32 + lq * 8];
#pragma unroll
        for (int n = 0; n < 2; ++n)
            b[n] = *(const short8*)&Wl[(wid * 32 + n * 16 + l15) * 64 + s * 32 + lq * 8];
#pragma unroll
        for (int m = 0; m < 4; ++m)
#pragma unroll
            for (int n = 0; n < 2; ++n)
                acc[m][n] = __builtin_amdgcn_mfma_f32_16x16x32_bf16(a[m], b[n], acc[m][n], 0, 0, 0);
    }
    float bb[2], cs[2] = {0.f, 0.f}, cq[2] = {0.f, 0.f};
#pragma unroll
    for (int n = 0; n < 2; ++n) bb[n] = b2f(b1[layer * 128 + wid * 32 + n * 16 + l15]);
#pragma unroll
    for (int m = 0; m < 4; ++m)
#pragma unroll
        for (int r = 0; r < 4; ++r) {
            int row = m * 16 + lq * 4 + r;
            if (row < nrows) {
#pragma unroll
                for (int n = 0; n < 2; ++n) {
                    float v = acc[m][n][r] + bb[n];
                    cs[n] += v; cq[n] += v * v;
                }
            }
        }
#pragma unroll
    for (int n = 0; n < 2; ++n) {
        ps[wid][lq][n * 16 + l15] = cs[n];
        qs[wid][lq][n * 16 + l15] = cq[n];
    }
    __syncthreads();
    if (threadIdx.x < 128) {
        int t = threadIdx.x, ww = t >> 5, cc = t & 31;   // col = ww*32 + cc = t
        float S = 0.f, Q = 0.f;
#pragma unroll
        for (int s4 = 0; s4 < 4; ++s4) { S += ps[ww][s4][cc]; Q += qs[ww][s4][cc]; }
        int sh = blockIdx.x & (NSHARD - 1);
        atomicAdd(&p1s[sh * 256 + t], S);
        atomicAdd(&p1s[sh * 256 + 128 + t], Q);
    }
}

// ---- MLP2 fused via MFMA: BN1 folded per-thread from sharded p1s; stats to p2s ------
// Writes PRE-affine z2 to Y. Weights direct from global; LDS 28.7KB (5 blk/CU).
__global__ __launch_bounds__(256) void k_mlp2(
    const bf16* __restrict__ W1T, const bf16* __restrict__ b1,
    const bf16* __restrict__ g1, const bf16* __restrict__ bb1,
    const float* __restrict__ p1s,
    const bf16* __restrict__ W2T, const bf16* __restrict__ bias2, int layer,
    const bf16* __restrict__ X, bf16* __restrict__ Y, float* __restrict__ p2s) {
    __shared__ bf16 zt[64 * 72];                         // 9216 B; reused to stage z2 out
    __shared__ bf16 yt[64 * 136];                        // 17408 B
    __shared__ float ps2[4][4][16];                      // 1024 B
    __shared__ float qs2[4][4][16];                      // 1024 B  -> total 28672 B
    const bf16* W1l = W1T + layer * 8192;
    const bf16* W2l = W2T + layer * 8192;
    int r0 = blockIdx.x * 64;
    int nrows = min(64, N_NODES - r0);
    for (int i = threadIdx.x; i < 512; i += 256) {
        int r = i >> 3, c = (i & 7) * 8;
        short8 v = {};
        if (r < nrows) v = *(const short8*)&X[(r0 + r) * 64 + c];
        *(short8*)&zt[r * 72 + c] = v;
    }
    __syncthreads();
    int wid = threadIdx.x >> 6;
    int l = threadIdx.x & 63;
    int l15 = l & 15, lq = l >> 4;
    {   // stage 1: 64x128 = 4 waves x (4 M-frags x 2 N-frags), K=64
        f32x4 acc[4][2];
#pragma unroll
        for (int m = 0; m < 4; ++m)
#pragma unroll
            for (int n = 0; n < 2; ++n) acc[m][n] = (f32x4){0.f, 0.f, 0.f, 0.f};
#pragma unroll
        for (int s = 0; s < 2; ++s) {
            short8 a[4], b[2];
#pragma unroll
            for (int m = 0; m < 4; ++m)
                a[m] = *(const short8*)&zt[(m * 16 + l15) * 72 + s * 32 + lq * 8];
#pragma unroll
            for (int n = 0; n < 2; ++n)
                b[n] = *(const short8*)&W1l[(wid * 32 + n * 16 + l15) * 64 + s * 32 + lq * 8];
#pragma unroll
            for (int m = 0; m < 4; ++m)
#pragma unroll
                for (int n = 0; n < 2; ++n)
                    acc[m][n] = __builtin_amdgcn_mfma_f32_16x16x32_bf16(a[m], b[n], acc[m][n], 0, 0, 0);
        }
        float aav[2], ccv[2], bbv[2];
#pragma unroll
        for (int n = 0; n < 2; ++n) {
            int col = wid * 32 + n * 16 + l15;
            float S = 0.f, Q = 0.f;
#pragma unroll
            for (int s4 = 0; s4 < NSHARD; ++s4) {
                S += p1s[s4 * 256 + col];
                Q += p1s[s4 * 256 + 128 + col];
            }
            float mean = S / (float)N_NODES;
            float var = fmaxf(Q / (float)N_NODES - mean * mean, 0.f);
            aav[n] = b2f(g1[layer * 128 + col]) * rsqrtf(var + 1e-5f);
            ccv[n] = b2f(bb1[layer * 128 + col]) - mean * aav[n];
            bbv[n] = b2f(b1[layer * 128 + col]);
        }
#pragma unroll
        for (int m = 0; m < 4; ++m)
#pragma unroll
            for (int n = 0; n < 2; ++n)
#pragma unroll
                for (int r = 0; r < 4; ++r) {
                    int row = m * 16 + lq * 4 + r;
                    float v = fmaxf(aav[n] * (acc[m][n][r] + bbv[n]) + ccv[n], 0.f);
                    yt[row * 136 + wid * 32 + n * 16 + l15] = f2b(v);
                }
    }
    __syncthreads();                                     // yt complete (cross-wave dep)
    {   // stage 2: 64x64 = 4 waves x (4 M-frags x 1 N-frag), K=128
        f32x4 acc2[4];
#pragma unroll
        for (int m = 0; m < 4; ++m) acc2[m] = (f32x4){0.f, 0.f, 0.f, 0.f};
#pragma unroll
        for (int s = 0; s < 4; ++s) {
            short8 a[4];
            short8 b = *(const short8*)&W2l[(wid * 16 + l15) * 128 + s * 32 + lq * 8];
#pragma unroll
            for (int m = 0; m < 4; ++m)
                a[m] = *(const short8*)&yt[(m * 16 + l15) * 136 + s * 32 + lq * 8];
#pragma unroll
            for (int m = 0; m < 4; ++m)
                acc2[m] = __builtin_amdgcn_mfma_f32_16x16x32_bf16(a[m], b, acc2[m], 0, 0, 0);
        }
        float bb2 = b2f(bias2[layer * 64 + wid * 16 + l15]);
        float cs = 0.f, cq = 0.f;
#pragma unroll
        for (int m = 0; m < 4; ++m)
#pragma unroll
            for (int r = 0; r < 4; ++r) {
                int row = m * 16 + lq * 4 + r;
                float v = acc2[m][r] + bb2;
                zt[row * 72 + wid * 16 + l15] = f2b(v);  // zt dead since stage-1 sync
                if (row < nrows) { cs += v; cq += v * v; }
            }
        ps2[wid][lq][l15] = cs;
        qs2[wid][lq][l15] = cq;
    }
    __syncthreads();
    for (int i = threadIdx.x; i < 512; i += 256) {       // coalesced z2 store via zt
        int r = i >> 3, c = (i & 7) * 8;
        if (r < nrows)
            *(short8*)&Y[(r0 + r) * 64 + c] = *(const short8*)&zt[r * 72 + c];
    }
    if (threadIdx.x < 64) {
        int ww = threadIdx.x >> 4, cc = threadIdx.x & 15; // col = ww*16+cc = threadIdx.x
        float S = 0.f, Q = 0.f;
#pragma unroll
        for (int s4 = 0; s4 < 4; ++s4) { S += ps2[ww][s4][cc]; Q += qs2[ww][s4][cc]; }
        int sh = blockIdx.x & (NSHARD - 1);
        atomicAdd(&p2s[(layer * NSHARD + sh) * 128 + threadIdx.x], S);
        atomicAdd(&p2s[(layer * NSHARD + sh) * 128 + 64 + threadIdx.x], Q);
    }
}

// ---- final: apply layer-3 affine (no relu), bf16 round, sanitize --------------------
// Sanitizer: NaN AND Inf/huge -> 0 (R17-proven; R18's NaN-only check leaked Inf).
__global__ void k_out(const bf16* __restrict__ P, const float* __restrict__ p2s,
                      const bf16* __restrict__ g2, const bf16* __restrict__ bb2,
                      const int* __restrict__ batch, float* __restrict__ out) {
    int tid = blockIdx.x * 256 + threadIdx.x;
    int c = tid & 63;
    const float* pp = p2s + 3 * NSHARD * 128;
    float S = 0.f, Q = 0.f;
#pragma unroll
    for (int s = 0; s < NSHARD; ++s) { S += pp[s * 128 + c]; Q += pp[s * 128 + 64 + c]; }
    float mean = S / (float)N_NODES;
    float var = fmaxf(Q / (float)N_NODES - mean * mean, 0.f);
    float av = b2f(g2[3 * 64 + c]) * rsqrtf(var + 1e-5f);
    float cv = b2f(bb2[3 * 64 + c]) - mean * av;
    float v = b2f(f2b(av * b2f(P[tid]) + cv));           // keep prior bf16 rounding
    out[tid] = (v != v || fabsf(v) > 1e20f) ? 0.f : v;
    if (tid < N_NODES) out[N_NODES * EMB + tid] = (float)batch[tid];
}

extern "C" void kernel_launch(void* const* d_in, const int* in_sizes, int n_in,
                              void* d_out, int out_size, void* d_ws, size_t ws_size,
                              hipStream_t stream) {
    (void)in_sizes; (void)n_in; (void)out_size; (void)ws_size;
    const int* x     = (const int*)d_in[0];
    const int* ei    = (const int*)d_in[1];
    const int* ea    = (const int*)d_in[2];
    const int* batch = (const int*)d_in[3];
    const bf16* aemb = (const bf16*)d_in[4];
    const bf16* bemb = (const bf16*)d_in[5];
    const bf16* eps  = (const bf16*)d_in[6];
    const bf16* W1   = (const bf16*)d_in[7];
    const bf16* b1   = (const bf16*)d_in[8];
    const bf16* g1   = (const bf16*)d_in[9];
    const bf16* bb1  = (const bf16*)d_in[10];
    const bf16* W2   = (const bf16*)d_in[11];
    const bf16* b2   = (const bf16*)d_in[12];
    const bf16* g2   = (const bf16*)d_in[13];
    const bf16* bb2  = (const bf16*)d_in[14];

    // R14/R17-measured ABI: d_out is fp32 storage (26 MB), compared in bf16 space.
    bf16* Y = (bf16*)d_ws;                               // pre-affine activations
    char* ob = (char*)d_out;
    bf16* X       = (bf16*)ob;                           // agg output [0 : 12.8M)
    int2* tmp8    = (int2*)ob;                           // scat1 payload [0 : 8M) (X dead)
    int*  tmpd    = (int*)(ob + 8000000);                // scat1 dst [8M : 12M)
    int*  offs    = (int*)(ob + 13200000);               // 100001 ints -> 13,600,004
    int2* csr     = (int2*)(ob + 14000008);              // 8 MB (src,combo) -> 22,000,008
    float* p1s    = (float*)(ob + 22000008);             // 16 shards x 256 f -> 22,016,392
    float* p2s    = (float*)(ob + 22016392);             // 4 x 16 x 128 f -> 22,049,160
    int*  bpart   = (int*)(ob + 22049160);               // 489*196 ints -> 22,432,536
    int*  bcnt    = (int*)(ob + 22432536);               // NBIN ints -> 22,433,320
    int*  bbase   = (int*)(ob + 22433320);               // NBIN ints -> 22,434,104
    bf16* w1t     = (bf16*)(ob + 22434112);              // 64 KB [L][128][64] (16B-align)
    bf16* w2t     = (bf16*)(ob + 22499648);              // 64 KB [L][64][128]
    bf16* cbt     = (bf16*)(ob + 22565184);              // 256 KB [L][512][64] -> 22,827,328

    k_atom<<<25000, 256, 0, stream>>>(x, aemb, Y);
    k_wt<<<128, 256, 0, stream>>>(W1, W2, w1t, w2t);
    k_bond<<<512, 256, 0, stream>>>(bemb, cbt);
    k_binc<<<NS1B, 256, 0, stream>>>(ei, bpart);
    k_binps<<<NBIN, 512, 0, stream>>>(bpart, bcnt);
    k_binbase<<<1, 256, 0, stream>>>(bcnt, bbase, offs);
    k_scat1<<<NS1B, 256, 0, stream>>>(ei, ea, bpart, bbase, tmp8, tmpd);
    k_scat2<<<NBIN, 512, 0, stream>>>(tmp8, tmpd, bbase, bcnt, offs, csr);

    for (int l = 0; l < NLAYER; ++l) {
        k_agg<<<25000, 256, 0, stream>>>(Y, offs, csr, cbt, eps,
                                         p2s, g2, bb2, l, X, p1s);
        k_mlp1s<<<NTILE, 256, 0, stream>>>(X, w1t, b1, l, p1s, p2s);
        k_mlp2<<<NTILE, 256, 0, stream>>>(w1t, b1, g1, bb1, p1s, w2t, b2, l, X, Y, p2s);
    }
    k_out<<<25000, 256, 0, stream>>>(Y, p2s, g2, bb2, batch, (float*)d_out);
}